// Round 1
// baseline (42.948 us; speedup 1.0000x reference)
//
#include <hip/hip_runtime.h>
#include <hip/hip_bf16.h>

// ---------------------------------------------------------------------------
// Fusion_12867722019048 on MFMA. B=65536, IN=64, H=16.
//
// Factorization (verified rounds 1-3): fusion[f = a*32 + mm*8 + l] =
//   X[a] * Y2[mm] * Z[l], X/Z pairwise maxes, Y2 quad maxes of the sigmoid
// projections (all positive, so maxpool of products factorizes).
//
// MFMA mapping (16x16x32 bf16, layouts HW-verified in learn_hip m89/m92):
//   A[m=lane&15][k=quad*8+j], B[n=lane&15][k=quad*8+j] (rows of W[n][k]),
//   D[m=quad*4+reg][n=lane&15].
//
// R4 restructure: the old kernel ran path2 AND path1 serially per wave
// (16 samples/wave -> 4096 waves total = 4 waves/SIMD, Occupancy 33%,
// MfmaUtil 4%, VALUBusy 17% -> latency-bound). Output halves are
// independent: out[:,0:64] needs only path2+mean (ng gemm), out[:,64:128]
// needs only path1. So now: block = 4 waves = 32 samples; waves 0-1 do
// path2 -> ng -> store left half, waves 2-3 do path1 -> store right half.
// 8192 waves total -> 8 waves/SIMD potential; still zero __syncthreads
// (all LDS wave-private). Weights pre-packed to bf16 frag tables in d_ws.
// ---------------------------------------------------------------------------

typedef __attribute__((ext_vector_type(8))) short short8;
typedef __attribute__((ext_vector_type(4))) float f32x4;

#define MFMA16(A, B, C) __builtin_amdgcn_mfma_f32_16x16x32_bf16((A), (B), (C), 0, 0, 0)

__device__ __forceinline__ float fast_sigmoid(float x) {
    return __builtin_amdgcn_rcpf(1.0f + __expf(-x));
}
__device__ __forceinline__ float gate(float x, float rm) {
    return x * fast_sigmoid(fabsf(x - rm));   // eval-mode normGate2
}
__device__ __forceinline__ float lrelu(float x) {
    return x >= 0.0f ? x : 0.01f * x;
}
__device__ __forceinline__ short f2bf(float f) {
    union { float f; unsigned u; } x; x.f = f;
    unsigned r = (x.u + 0x7FFF + ((x.u >> 16) & 1)) >> 16;  // RNE
    return (short)r;
}
__device__ __forceinline__ short8 pack8(const float* xs) {
    union { short8 s; __hip_bfloat162 h[4]; } u;
    #pragma unroll
    for (int i = 0; i < 4; ++i) {
        float2 t; t.x = xs[2 * i]; t.y = xs[2 * i + 1];
        u.h[i] = __float22bfloat162_rn(t);
    }
    return u.s;
}
__device__ __forceinline__ f32x4 pmax_xor(f32x4 v, int mask) {
    f32x4 r;
    #pragma unroll
    for (int i = 0; i < 4; ++i) r[i] = fmaxf(v[i], __shfl_xor(v[i], mask, 64));
    return r;
}

// sigmoid(x @ W^T + b): returns H[sample = quad*4+reg][unit = lane&15]
__device__ __forceinline__ f32x4 proj_mfma(const float* __restrict__ xbase,
                                           const short8* __restrict__ wfr,
                                           const float* __restrict__ bias,
                                           int lane) {
    const int m = lane & 15, quad = lane >> 4;
    f32x4 acc; acc[0] = acc[1] = acc[2] = acc[3] = 0.0f;
    #pragma unroll
    for (int t = 0; t < 2; ++t) {
        const float4* p = (const float4*)(xbase + m * 64 + t * 32 + quad * 8);
        float4 u0 = p[0], u1 = p[1];
        float xs[8] = {u0.x, u0.y, u0.z, u0.w, u1.x, u1.y, u1.z, u1.w};
        acc = MFMA16(pack8(xs), wfr[t * 64 + lane], acc);
    }
    const float bn = bias[m];
    f32x4 h;
    #pragma unroll
    for (int r = 0; r < 4; ++r) h[r] = fast_sigmoid(acc[r] + bn);
    return h;
}

// Pool + transpose into wave-private LDS: X8T[8][16], Y2T[4][16], Z8T[8][16].
// Duplicate-lane writes hit the same address with the same value (benign).
__device__ __forceinline__ void stage_pools(f32x4 hx, f32x4 hy, f32x4 hz, int lane,
                                            float* __restrict__ sX,
                                            float* __restrict__ sY,
                                            float* __restrict__ sZ) {
    const int quad = lane >> 4, ln = lane & 15;
    f32x4 X = pmax_xor(hx, 1);
    f32x4 Y = pmax_xor(pmax_xor(hy, 1), 2);
    f32x4 Z = pmax_xor(hz, 1);
    #pragma unroll
    for (int r = 0; r < 4; ++r) {
        const int sm = quad * 4 + r;
        sX[(ln >> 1) * 16 + sm] = X[r];
        sY[(ln >> 2) * 16 + sm] = Y[r];
        sZ[(ln >> 1) * 16 + sm] = Z[r];
    }
}

// acc[nt] = D tile [16 samples][16 cols], cols nt*16+lane&15; K=256 in 8 steps.
__device__ __forceinline__ void fusion_mfma(const short8* __restrict__ wfr,
                                            const float* __restrict__ bias,
                                            const float* __restrict__ sX,
                                            const float* __restrict__ sY,
                                            const float* __restrict__ sZ,
                                            int lane, f32x4 acc[4]) {
    const int m = lane & 15, quad = lane >> 4;
    #pragma unroll
    for (int nt = 0; nt < 4; ++nt) {
        const float bb = bias[nt * 16 + m];
        acc[nt][0] = acc[nt][1] = acc[nt][2] = acc[nt][3] = bb;
    }
    float zr[8];
    #pragma unroll
    for (int j = 0; j < 8; ++j) zr[j] = sZ[j * 16 + m];
    const float yq = sY[quad * 16 + m];
    #pragma unroll
    for (int t = 0; t < 8; ++t) {
        const float xy = sX[t * 16 + m] * yq;
        float p[8];
        #pragma unroll
        for (int j = 0; j < 8; ++j) p[j] = xy * zr[j];
        const short8 af = pack8(p);
        #pragma unroll
        for (int nt = 0; nt < 4; ++nt)
            acc[nt] = MFMA16(af, wfr[(t * 4 + nt) * 64 + lane], acc[nt]);
    }
}

__global__ __launch_bounds__(256, 8)
void fused_fwd(const float* __restrict__ a,  const float* __restrict__ v,
               const float* __restrict__ l,  const float* __restrict__ pa,
               const float* __restrict__ pv, const float* __restrict__ pl,
               const float* __restrict__ mean,
               const float* __restrict__ ba,  const float* __restrict__ bv_,
               const float* __restrict__ bl_, const float* __restrict__ bap,
               const float* __restrict__ bvp, const float* __restrict__ blp,
               const float* __restrict__ bf1, const float* __restrict__ bfp1,
               const float* __restrict__ bng,
               const float* __restrict__ rm1, const float* __restrict__ rm2,
               const short* __restrict__ ws, float* __restrict__ out) {
    __shared__ __align__(16) float sPool[4 * 320];   // per wave: X8T|Y2T|Z8T
    __shared__ __align__(16) short sF2[2 * 1280];    // waves 0-1: [16][80] bf16

    const int tid = threadIdx.x;
    const int lane = tid & 63;
    const int w = tid >> 6;           // 0..3
    const int m = lane & 15;
    const int quad = lane >> 4;
    const int wi = w & 1;             // index within path group
    const int srow0 = blockIdx.x * 32 + wi * 16;   // wave's first sample

    float* sX = sPool + w * 320;
    float* sY = sX + 128;
    float* sZ = sY + 64;

    const short8* projFr = (const short8*)ws;             // 6 x 128 frags
    const short8* wfFr   = (const short8*)(ws + 6144);    // 32 x 64
    const short8* wfpFr  = (const short8*)(ws + 22528);   // 32 x 64
    const short8* wngFr  = (const short8*)(ws + 38912);   // 16 x 64

    if (w < 2) {
        // ======= path 2 (p_a,p_v,p_l) -> fusion_2 -> ng gemm -> out[:,0:64) =======
        {
            f32x4 hx = proj_mfma(pa + (size_t)srow0 * 64, projFr + 3 * 128, bap, lane);
            f32x4 hy = proj_mfma(pv + (size_t)srow0 * 64, projFr + 4 * 128, bvp, lane);
            f32x4 hz = proj_mfma(pl + (size_t)srow0 * 64, projFr + 5 * 128, blp, lane);
            stage_pools(hx, hy, hz, lane, sX, sY, sZ);
        }
        f32x4 f2[4];
        fusion_mfma(wfpFr, bfp1, sX, sY, sZ, lane, f2);

        // gate(lrelu(fusion_2), rm1[0:64]) -> wave-private bf16 tile [16][80]
        short* sF = sF2 + wi * 1280;
        #pragma unroll
        for (int nt = 0; nt < 4; ++nt) {
            const float r1 = rm1[nt * 16 + m];
            #pragma unroll
            for (int r = 0; r < 4; ++r) {
                const float g = gate(lrelu(f2[nt][r]), r1);
                sF[(quad * 4 + r) * 80 + nt * 16 + m] = f2bf(g);
            }
        }

        // ng gemm: h = concat(F2g, gated mean) @ Wng^T + bng
        f32x4 h[4];
        #pragma unroll
        for (int nt = 0; nt < 4; ++nt) {
            const float bb = bng[nt * 16 + m];
            h[nt][0] = h[nt][1] = h[nt][2] = h[nt][3] = bb;
        }
        #pragma unroll
        for (int t = 0; t < 2; ++t) {   // k = 0..63 from F2g tile (LDS)
            const short8 af = *(const short8*)(sF + m * 80 + t * 32 + quad * 8);
            #pragma unroll
            for (int nt = 0; nt < 4; ++nt)
                h[nt] = MFMA16(af, wngFr[(t * 4 + nt) * 64 + lane], h[nt]);
        }
        #pragma unroll
        for (int t2 = 0; t2 < 2; ++t2) {  // k = 64..127 from gated mean (global)
            const float4* mp = (const float4*)(mean + (size_t)(srow0 + m) * 64 + t2 * 32 + quad * 8);
            float4 u0 = mp[0], u1 = mp[1];
            const float4* rp = (const float4*)(rm1 + 64 + t2 * 32 + quad * 8);
            float4 r0 = rp[0], r1 = rp[1];
            float g[8] = { gate(u0.x, r0.x), gate(u0.y, r0.y), gate(u0.z, r0.z), gate(u0.w, r0.w),
                           gate(u1.x, r1.x), gate(u1.y, r1.y), gate(u1.z, r1.z), gate(u1.w, r1.w) };
            const short8 af = pack8(g);
            #pragma unroll
            for (int nt = 0; nt < 4; ++nt)
                h[nt] = MFMA16(af, wngFr[((2 + t2) * 4 + nt) * 64 + lane], h[nt]);
        }

        // store left half: gate(h, rm2[0:64])
        #pragma unroll
        for (int nt = 0; nt < 4; ++nt) {
            const float r2a = rm2[nt * 16 + m];
            #pragma unroll
            for (int r = 0; r < 4; ++r) {
                const size_t row = (size_t)(srow0 + quad * 4 + r) * 128;
                out[row + nt * 16 + m] = gate(h[nt][r], r2a);
            }
        }
    } else {
        // ======= path 1 (a,v,l) -> fusion_1 -> out[:,64:128) =======
        {
            f32x4 hx = proj_mfma(a + (size_t)srow0 * 64, projFr + 0 * 128, ba, lane);
            f32x4 hy = proj_mfma(v + (size_t)srow0 * 64, projFr + 1 * 128, bv_, lane);
            f32x4 hz = proj_mfma(l + (size_t)srow0 * 64, projFr + 2 * 128, bl_, lane);
            stage_pools(hx, hy, hz, lane, sX, sY, sZ);
        }
        f32x4 f1[4];
        fusion_mfma(wfFr, bf1, sX, sY, sZ, lane, f1);

        // store right half: gate(lrelu(f1), rm2[64:128])
        #pragma unroll
        for (int nt = 0; nt < 4; ++nt) {
            const float r2b = rm2[64 + nt * 16 + m];
            #pragma unroll
            for (int r = 0; r < 4; ++r) {
                const size_t row = (size_t)(srow0 + quad * 4 + r) * 128;
                out[row + 64 + nt * 16 + m] = gate(lrelu(f1[nt][r]), r2b);
            }
        }
    }
}

// Pack all weights into bf16 frag-ordered tables:
//   frag element for (t, nt, lane, j): row = nt*16 + (lane&15),
//   col = t*32 + (lane>>4)*8 + j  -> B[n][k] rows of each W.
// Layout (shorts): [0,6144) six 16x64 projs (Wa,Wv,Wl,Wap,Wvp,Wlp);
// [6144,22528) Wf1; [22528,38912) Wfp1; [38912,47104) Wng.
__global__ void build_frags(const float* __restrict__ Wa,  const float* __restrict__ Wv,
                            const float* __restrict__ Wl,  const float* __restrict__ Wap,
                            const float* __restrict__ Wvp, const float* __restrict__ Wlp,
                            const float* __restrict__ Wf1, const float* __restrict__ Wfp1,
                            const float* __restrict__ Wng, short* __restrict__ ws) {
    const int i = blockIdx.x * 256 + threadIdx.x;
    if (i >= 47104) return;
    float val;
    if (i < 6144) {
        const float* W[6] = {Wa, Wv, Wl, Wap, Wvp, Wlp};
        const int mi = i >> 10, r = i & 1023;
        const int t = r >> 9, lane = (r >> 3) & 63, j = r & 7;
        val = W[mi][(lane & 15) * 64 + t * 32 + (lane >> 4) * 8 + j];
    } else if (i < 38912) {
        int r = i - 6144;
        const float* W = (r < 16384) ? Wf1 : Wfp1;
        r &= 16383;
        const int tn = r >> 9, lane = (r >> 3) & 63, j = r & 7;
        const int t = tn >> 2, nt = tn & 3;
        val = W[(nt * 16 + (lane & 15)) * 256 + t * 32 + (lane >> 4) * 8 + j];
    } else {
        const int r = i - 38912;
        const int tn = r >> 9, lane = (r >> 3) & 63, j = r & 7;
        const int t = tn >> 2, nt = tn & 3;
        val = Wng[(nt * 16 + (lane & 15)) * 128 + t * 32 + (lane >> 4) * 8 + j];
    }
    ws[i] = f2bf(val);
}

extern "C" void kernel_launch(void* const* d_in, const int* in_sizes, int n_in,
                              void* d_out, int out_size, void* d_ws, size_t ws_size,
                              hipStream_t stream) {
    const float* a    = (const float*)d_in[0];
    const float* v    = (const float*)d_in[1];
    const float* l    = (const float*)d_in[2];
    const float* pa   = (const float*)d_in[3];
    const float* pv   = (const float*)d_in[4];
    const float* pl   = (const float*)d_in[5];
    const float* mean = (const float*)d_in[6];
    const float* Wa   = (const float*)d_in[7];
    const float* ba   = (const float*)d_in[8];
    const float* Wv   = (const float*)d_in[9];
    const float* bv   = (const float*)d_in[10];
    const float* Wl   = (const float*)d_in[11];
    const float* bl   = (const float*)d_in[12];
    const float* Wap  = (const float*)d_in[13];
    const float* bap  = (const float*)d_in[14];
    const float* Wvp  = (const float*)d_in[15];
    const float* bvp  = (const float*)d_in[16];
    const float* Wlp  = (const float*)d_in[17];
    const float* blp  = (const float*)d_in[18];
    const float* Wf1  = (const float*)d_in[19];
    const float* bf1  = (const float*)d_in[20];
    const float* Wfp1 = (const float*)d_in[21];
    const float* bfp1 = (const float*)d_in[22];
    const float* Wng  = (const float*)d_in[23];
    const float* bng  = (const float*)d_in[24];
    const float* rm1  = (const float*)d_in[25];
    const float* rm2  = (const float*)d_in[26];

    short* ws = (short*)d_ws;  // 47104 shorts = 92 KiB

    build_frags<<<184, 256, 0, stream>>>(Wa, Wv, Wl, Wap, Wvp, Wlp,
                                         Wf1, Wfp1, Wng, ws);
    fused_fwd<<<2048, 256, 0, stream>>>(a, v, l, pa, pv, pl, mean,
                                        ba, bv, bl, bap, bvp, blp,
                                        bf1, bfp1, bng, rm1, rm2,
                                        ws, (float*)d_out);
}

// Round 2
// 39.885 us; speedup vs baseline: 1.0768x; 1.0768x over previous
//
#include <hip/hip_runtime.h>
#include <hip/hip_bf16.h>

// ---------------------------------------------------------------------------
// Fusion_12867722019048 on MFMA. B=65536, IN=64, H=16.
//
// Factorization (verified rounds 1-3): fusion[f = a*32 + mm*8 + l] =
//   X[a] * Y2[mm] * Z[l], X/Z pairwise maxes, Y2 quad maxes of the sigmoid
// projections (all positive, so maxpool of products factorizes).
//
// MFMA mapping (16x16x32 bf16, layouts HW-verified in learn_hip m89/m92):
//   A[m=lane&15][k=quad*8+j], B[n=lane&15][k=quad*8+j] (rows of W[n][k]),
//   D[m=quad*4+reg][n=lane&15].
//
// R5 restructure: R4 (path-split, 16 samples/wave, 8 waves/SIMD) showed
// occupancy 33->56% but dur unchanged and VGPR forced to 32 -> the kernel is
// ILP-bound on the weight-fragment load chain (each B-frag loaded once, used
// once, serially at L2 latency), not TLP-bound. Now: 32 samples/wave (two
// 16-row M-tiles), __launch_bounds__(256,4) for a 128-VGPR budget. Every
// weight frag is loaded once and feeds TWO MFMAs (tile0+tile1), halving frag
// traffic and exposed load latency; the register budget lets the compiler
// pipeline frag loads deep. Path split kept: waves 0-1 = path2 -> ng ->
// out[:,0:64), waves 2-3 = path1 -> out[:,64:128). Zero __syncthreads (all
// LDS wave-private). Weights pre-packed to bf16 frag tables in d_ws.
// ---------------------------------------------------------------------------

typedef __attribute__((ext_vector_type(8))) short short8;
typedef __attribute__((ext_vector_type(4))) float f32x4;

#define MFMA16(A, B, C) __builtin_amdgcn_mfma_f32_16x16x32_bf16((A), (B), (C), 0, 0, 0)

__device__ __forceinline__ float fast_sigmoid(float x) {
    return __builtin_amdgcn_rcpf(1.0f + __expf(-x));
}
__device__ __forceinline__ float gate(float x, float rm) {
    return x * fast_sigmoid(fabsf(x - rm));   // eval-mode normGate2
}
__device__ __forceinline__ float lrelu(float x) {
    return x >= 0.0f ? x : 0.01f * x;
}
__device__ __forceinline__ short f2bf(float f) {
    union { float f; unsigned u; } x; x.f = f;
    unsigned r = (x.u + 0x7FFF + ((x.u >> 16) & 1)) >> 16;  // RNE
    return (short)r;
}
__device__ __forceinline__ short8 pack8(const float* xs) {
    union { short8 s; __hip_bfloat162 h[4]; } u;
    #pragma unroll
    for (int i = 0; i < 4; ++i) {
        float2 t; t.x = xs[2 * i]; t.y = xs[2 * i + 1];
        u.h[i] = __float22bfloat162_rn(t);
    }
    return u.s;
}
__device__ __forceinline__ f32x4 pmax_xor(f32x4 v, int mask) {
    f32x4 r;
    #pragma unroll
    for (int i = 0; i < 4; ++i) r[i] = fmaxf(v[i], __shfl_xor(v[i], mask, 64));
    return r;
}

// sigmoid(x @ W^T + b) for TWO 16-row tiles sharing each weight frag.
// h0/h1: H[sample = quad*4+reg][unit = lane&15] for tile0 (rows xbase) and
// tile1 (rows xbase + 16*64).
__device__ __forceinline__ void proj_mfma2(const float* __restrict__ xbase,
                                           const short8* __restrict__ wfr,
                                           const float* __restrict__ bias,
                                           int lane, f32x4& h0, f32x4& h1) {
    const int m = lane & 15, quad = lane >> 4;
    f32x4 a0; a0[0] = a0[1] = a0[2] = a0[3] = 0.0f;
    f32x4 a1 = a0;
    #pragma unroll
    for (int t = 0; t < 2; ++t) {
        const float4* p0 = (const float4*)(xbase + m * 64 + t * 32 + quad * 8);
        const float4* p1 = (const float4*)(xbase + (16 + m) * 64 + t * 32 + quad * 8);
        float4 u0 = p0[0], u1 = p0[1];
        float4 w0 = p1[0], w1 = p1[1];
        const short8 frag = wfr[t * 64 + lane];
        float xs0[8] = {u0.x, u0.y, u0.z, u0.w, u1.x, u1.y, u1.z, u1.w};
        float xs1[8] = {w0.x, w0.y, w0.z, w0.w, w1.x, w1.y, w1.z, w1.w};
        a0 = MFMA16(pack8(xs0), frag, a0);
        a1 = MFMA16(pack8(xs1), frag, a1);
    }
    const float bn = bias[m];
    #pragma unroll
    for (int r = 0; r < 4; ++r) {
        h0[r] = fast_sigmoid(a0[r] + bn);
        h1[r] = fast_sigmoid(a1[r] + bn);
    }
}

// Pool + transpose into wave-private LDS: X8T[8][16], Y2T[4][16], Z8T[8][16].
// Duplicate-lane writes hit the same address with the same value (benign).
__device__ __forceinline__ void stage_pools(f32x4 hx, f32x4 hy, f32x4 hz, int lane,
                                            float* __restrict__ sX,
                                            float* __restrict__ sY,
                                            float* __restrict__ sZ) {
    const int quad = lane >> 4, ln = lane & 15;
    f32x4 X = pmax_xor(hx, 1);
    f32x4 Y = pmax_xor(pmax_xor(hy, 1), 2);
    f32x4 Z = pmax_xor(hz, 1);
    #pragma unroll
    for (int r = 0; r < 4; ++r) {
        const int sm = quad * 4 + r;
        sX[(ln >> 1) * 16 + sm] = X[r];
        sY[(ln >> 2) * 16 + sm] = Y[r];
        sZ[(ln >> 1) * 16 + sm] = Z[r];
    }
}

// Two-tile fusion GEMM: acc{0,1}[nt] = D tiles [16 samples][16 cols],
// cols nt*16+lane&15; K=256 in 8 steps; each weight frag feeds both tiles.
__device__ __forceinline__ void fusion_mfma2(const short8* __restrict__ wfr,
                                             const float* __restrict__ bias,
                                             const float* __restrict__ sP0,
                                             const float* __restrict__ sP1,
                                             int lane,
                                             f32x4 acc0[4], f32x4 acc1[4]) {
    const int m = lane & 15, quad = lane >> 4;
    const float* sX0 = sP0;       const float* sY0 = sP0 + 128; const float* sZ0 = sP0 + 192;
    const float* sX1 = sP1;       const float* sY1 = sP1 + 128; const float* sZ1 = sP1 + 192;
    #pragma unroll
    for (int nt = 0; nt < 4; ++nt) {
        const float bb = bias[nt * 16 + m];
        acc0[nt][0] = acc0[nt][1] = acc0[nt][2] = acc0[nt][3] = bb;
        acc1[nt][0] = acc1[nt][1] = acc1[nt][2] = acc1[nt][3] = bb;
    }
    float zr0[8], zr1[8];
    #pragma unroll
    for (int j = 0; j < 8; ++j) { zr0[j] = sZ0[j * 16 + m]; zr1[j] = sZ1[j * 16 + m]; }
    const float yq0 = sY0[quad * 16 + m];
    const float yq1 = sY1[quad * 16 + m];
    #pragma unroll
    for (int t = 0; t < 8; ++t) {
        const float xy0 = sX0[t * 16 + m] * yq0;
        const float xy1 = sX1[t * 16 + m] * yq1;
        float p0[8], p1[8];
        #pragma unroll
        for (int j = 0; j < 8; ++j) { p0[j] = xy0 * zr0[j]; p1[j] = xy1 * zr1[j]; }
        const short8 af0 = pack8(p0);
        const short8 af1 = pack8(p1);
        #pragma unroll
        for (int nt = 0; nt < 4; ++nt) {
            const short8 frag = wfr[(t * 4 + nt) * 64 + lane];
            acc0[nt] = MFMA16(af0, frag, acc0[nt]);
            acc1[nt] = MFMA16(af1, frag, acc1[nt]);
        }
    }
}

__global__ __launch_bounds__(256, 4)
void fused_fwd(const float* __restrict__ a,  const float* __restrict__ v,
               const float* __restrict__ l,  const float* __restrict__ pa,
               const float* __restrict__ pv, const float* __restrict__ pl,
               const float* __restrict__ mean,
               const float* __restrict__ ba,  const float* __restrict__ bv_,
               const float* __restrict__ bl_, const float* __restrict__ bap,
               const float* __restrict__ bvp, const float* __restrict__ blp,
               const float* __restrict__ bf1, const float* __restrict__ bfp1,
               const float* __restrict__ bng,
               const float* __restrict__ rm1, const float* __restrict__ rm2,
               const short* __restrict__ ws, float* __restrict__ out) {
    __shared__ __align__(16) float sPool[4 * 2 * 320];   // per wave, per tile
    __shared__ __align__(16) short sF2[2 * 2 * 1280];    // waves 0-1, per tile

    const int tid = threadIdx.x;
    const int lane = tid & 63;
    const int w = tid >> 6;           // 0..3
    const int m = lane & 15;
    const int quad = lane >> 4;
    const int wi = w & 1;             // index within path group
    const int srow0 = blockIdx.x * 64 + wi * 32;   // wave's first sample (2 tiles)

    float* sP0 = sPool + w * 640;     // tile0 pools: X[128] Y[64] Z[128]
    float* sP1 = sP0 + 320;           // tile1 pools

    const short8* projFr = (const short8*)ws;             // 6 x 128 frags
    const short8* wfFr   = (const short8*)(ws + 6144);    // 32 x 64
    const short8* wfpFr  = (const short8*)(ws + 22528);   // 32 x 64
    const short8* wngFr  = (const short8*)(ws + 38912);   // 16 x 64

    if (w < 2) {
        // ===== path 2 (p_a,p_v,p_l) -> fusion_2 -> ng gemm -> out[:,0:64) =====
        {
            f32x4 hx0, hx1, hy0, hy1, hz0, hz1;
            proj_mfma2(pa + (size_t)srow0 * 64, projFr + 3 * 128, bap, lane, hx0, hx1);
            proj_mfma2(pv + (size_t)srow0 * 64, projFr + 4 * 128, bvp, lane, hy0, hy1);
            proj_mfma2(pl + (size_t)srow0 * 64, projFr + 5 * 128, blp, lane, hz0, hz1);
            stage_pools(hx0, hy0, hz0, lane, sP0, sP0 + 128, sP0 + 192);
            stage_pools(hx1, hy1, hz1, lane, sP1, sP1 + 128, sP1 + 192);
        }
        f32x4 f20[4], f21[4];
        fusion_mfma2(wfpFr, bfp1, sP0, sP1, lane, f20, f21);

        // gate(lrelu(fusion_2), rm1[0:64]) -> wave-private bf16 tiles [16][80]
        short* sF0 = sF2 + wi * 2560;
        short* sF1 = sF0 + 1280;
        #pragma unroll
        for (int nt = 0; nt < 4; ++nt) {
            const float r1 = rm1[nt * 16 + m];
            #pragma unroll
            for (int r = 0; r < 4; ++r) {
                sF0[(quad * 4 + r) * 80 + nt * 16 + m] = f2bf(gate(lrelu(f20[nt][r]), r1));
                sF1[(quad * 4 + r) * 80 + nt * 16 + m] = f2bf(gate(lrelu(f21[nt][r]), r1));
            }
        }

        // ng gemm: h = concat(F2g, gated mean) @ Wng^T + bng, two tiles
        f32x4 h0[4], h1[4];
        #pragma unroll
        for (int nt = 0; nt < 4; ++nt) {
            const float bb = bng[nt * 16 + m];
            h0[nt][0] = h0[nt][1] = h0[nt][2] = h0[nt][3] = bb;
            h1[nt][0] = h1[nt][1] = h1[nt][2] = h1[nt][3] = bb;
        }
        #pragma unroll
        for (int t = 0; t < 2; ++t) {   // k = 0..63 from F2g tiles (LDS)
            const short8 af0 = *(const short8*)(sF0 + m * 80 + t * 32 + quad * 8);
            const short8 af1 = *(const short8*)(sF1 + m * 80 + t * 32 + quad * 8);
            #pragma unroll
            for (int nt = 0; nt < 4; ++nt) {
                const short8 frag = wngFr[(t * 4 + nt) * 64 + lane];
                h0[nt] = MFMA16(af0, frag, h0[nt]);
                h1[nt] = MFMA16(af1, frag, h1[nt]);
            }
        }
        #pragma unroll
        for (int t2 = 0; t2 < 2; ++t2) {  // k = 64..127 from gated mean (global)
            const float4* rp = (const float4*)(rm1 + 64 + t2 * 32 + quad * 8);
            float4 r0 = rp[0], r1 = rp[1];
            const float4* mp0 = (const float4*)(mean + (size_t)(srow0 + m) * 64 + t2 * 32 + quad * 8);
            const float4* mp1 = (const float4*)(mean + (size_t)(srow0 + 16 + m) * 64 + t2 * 32 + quad * 8);
            float4 u0 = mp0[0], u1 = mp0[1];
            float4 w0 = mp1[0], w1 = mp1[1];
            float g0[8] = { gate(u0.x, r0.x), gate(u0.y, r0.y), gate(u0.z, r0.z), gate(u0.w, r0.w),
                            gate(u1.x, r1.x), gate(u1.y, r1.y), gate(u1.z, r1.z), gate(u1.w, r1.w) };
            float g1[8] = { gate(w0.x, r0.x), gate(w0.y, r0.y), gate(w0.z, r0.z), gate(w0.w, r0.w),
                            gate(w1.x, r1.x), gate(w1.y, r1.y), gate(w1.z, r1.z), gate(w1.w, r1.w) };
            const short8 af0 = pack8(g0);
            const short8 af1 = pack8(g1);
            #pragma unroll
            for (int nt = 0; nt < 4; ++nt) {
                const short8 frag = wngFr[((2 + t2) * 4 + nt) * 64 + lane];
                h0[nt] = MFMA16(af0, frag, h0[nt]);
                h1[nt] = MFMA16(af1, frag, h1[nt]);
            }
        }

        // store left halves: gate(h, rm2[0:64])
        #pragma unroll
        for (int nt = 0; nt < 4; ++nt) {
            const float r2a = rm2[nt * 16 + m];
            #pragma unroll
            for (int r = 0; r < 4; ++r) {
                const size_t row0 = (size_t)(srow0 + quad * 4 + r) * 128;
                const size_t row1 = (size_t)(srow0 + 16 + quad * 4 + r) * 128;
                out[row0 + nt * 16 + m] = gate(h0[nt][r], r2a);
                out[row1 + nt * 16 + m] = gate(h1[nt][r], r2a);
            }
        }
    } else {
        // ===== path 1 (a,v,l) -> fusion_1 -> out[:,64:128) =====
        {
            f32x4 hx0, hx1, hy0, hy1, hz0, hz1;
            proj_mfma2(a + (size_t)srow0 * 64, projFr + 0 * 128, ba, lane, hx0, hx1);
            proj_mfma2(v + (size_t)srow0 * 64, projFr + 1 * 128, bv_, lane, hy0, hy1);
            proj_mfma2(l + (size_t)srow0 * 64, projFr + 2 * 128, bl_, lane, hz0, hz1);
            stage_pools(hx0, hy0, hz0, lane, sP0, sP0 + 128, sP0 + 192);
            stage_pools(hx1, hy1, hz1, lane, sP1, sP1 + 128, sP1 + 192);
        }
        f32x4 f10[4], f11[4];
        fusion_mfma2(wfFr, bf1, sP0, sP1, lane, f10, f11);

        // store right halves: gate(lrelu(f1), rm2[64:128])
        #pragma unroll
        for (int nt = 0; nt < 4; ++nt) {
            const float r2b = rm2[64 + nt * 16 + m];
            #pragma unroll
            for (int r = 0; r < 4; ++r) {
                const size_t row0 = (size_t)(srow0 + quad * 4 + r) * 128;
                const size_t row1 = (size_t)(srow0 + 16 + quad * 4 + r) * 128;
                out[row0 + 64 + nt * 16 + m] = gate(lrelu(f10[nt][r]), r2b);
                out[row1 + 64 + nt * 16 + m] = gate(lrelu(f11[nt][r]), r2b);
            }
        }
    }
}

// Pack all weights into bf16 frag-ordered tables:
//   frag element for (t, nt, lane, j): row = nt*16 + (lane&15),
//   col = t*32 + (lane>>4)*8 + j  -> B[n][k] rows of each W.
// Layout (shorts): [0,6144) six 16x64 projs (Wa,Wv,Wl,Wap,Wvp,Wlp);
// [6144,22528) Wf1; [22528,38912) Wfp1; [38912,47104) Wng.
__global__ void build_frags(const float* __restrict__ Wa,  const float* __restrict__ Wv,
                            const float* __restrict__ Wl,  const float* __restrict__ Wap,
                            const float* __restrict__ Wvp, const float* __restrict__ Wlp,
                            const float* __restrict__ Wf1, const float* __restrict__ Wfp1,
                            const float* __restrict__ Wng, short* __restrict__ ws) {
    const int i = blockIdx.x * 256 + threadIdx.x;
    if (i >= 47104) return;
    float val;
    if (i < 6144) {
        const float* W[6] = {Wa, Wv, Wl, Wap, Wvp, Wlp};
        const int mi = i >> 10, r = i & 1023;
        const int t = r >> 9, lane = (r >> 3) & 63, j = r & 7;
        val = W[mi][(lane & 15) * 64 + t * 32 + (lane >> 4) * 8 + j];
    } else if (i < 38912) {
        int r = i - 6144;
        const float* W = (r < 16384) ? Wf1 : Wfp1;
        r &= 16383;
        const int tn = r >> 9, lane = (r >> 3) & 63, j = r & 7;
        const int t = tn >> 2, nt = tn & 3;
        val = W[(nt * 16 + (lane & 15)) * 256 + t * 32 + (lane >> 4) * 8 + j];
    } else {
        const int r = i - 38912;
        const int tn = r >> 9, lane = (r >> 3) & 63, j = r & 7;
        const int t = tn >> 2, nt = tn & 3;
        val = Wng[(nt * 16 + (lane & 15)) * 128 + t * 32 + (lane >> 4) * 8 + j];
    }
    ws[i] = f2bf(val);
}

extern "C" void kernel_launch(void* const* d_in, const int* in_sizes, int n_in,
                              void* d_out, int out_size, void* d_ws, size_t ws_size,
                              hipStream_t stream) {
    const float* a    = (const float*)d_in[0];
    const float* v    = (const float*)d_in[1];
    const float* l    = (const float*)d_in[2];
    const float* pa   = (const float*)d_in[3];
    const float* pv   = (const float*)d_in[4];
    const float* pl   = (const float*)d_in[5];
    const float* mean = (const float*)d_in[6];
    const float* Wa   = (const float*)d_in[7];
    const float* ba   = (const float*)d_in[8];
    const float* Wv   = (const float*)d_in[9];
    const float* bv   = (const float*)d_in[10];
    const float* Wl   = (const float*)d_in[11];
    const float* bl   = (const float*)d_in[12];
    const float* Wap  = (const float*)d_in[13];
    const float* bap  = (const float*)d_in[14];
    const float* Wvp  = (const float*)d_in[15];
    const float* bvp  = (const float*)d_in[16];
    const float* Wlp  = (const float*)d_in[17];
    const float* blp  = (const float*)d_in[18];
    const float* Wf1  = (const float*)d_in[19];
    const float* bf1  = (const float*)d_in[20];
    const float* Wfp1 = (const float*)d_in[21];
    const float* bfp1 = (const float*)d_in[22];
    const float* Wng  = (const float*)d_in[23];
    const float* bng  = (const float*)d_in[24];
    const float* rm1  = (const float*)d_in[25];
    const float* rm2  = (const float*)d_in[26];

    short* ws = (short*)d_ws;  // 47104 shorts = 92 KiB

    build_frags<<<184, 256, 0, stream>>>(Wa, Wv, Wl, Wap, Wvp, Wlp,
                                         Wf1, Wfp1, Wng, ws);
    fused_fwd<<<1024, 256, 0, stream>>>(a, v, l, pa, pv, pl, mean,
                                        ba, bv, bl, bap, bvp, blp,
                                        bf1, bfp1, bng, rm1, rm2,
                                        ws, (float*)d_out);
}